// Round 1
// baseline (1094.189 us; speedup 1.0000x reference)
//
#include <hip/hip_runtime.h>
#include <math.h>

// ---------------- CSR build ----------------

__global__ __launch_bounds__(256) void hist_k(const int* __restrict__ dst, int* __restrict__ cnt, int E){
  int e = blockIdx.x*256 + threadIdx.x;
  if (e < E) atomicAdd(&cnt[dst[e]], 1);
}

__global__ __launch_bounds__(256) void blocksum_k(const int* __restrict__ cnt, int* __restrict__ bsum, int N){
  int i = blockIdx.x*256 + threadIdx.x;
  int v = (i < N) ? cnt[i] : 0;
  #pragma unroll
  for (int off = 32; off; off >>= 1) v += __shfl_down(v, off, 64);
  __shared__ int s[4];
  if ((threadIdx.x & 63) == 0) s[threadIdx.x >> 6] = v;
  __syncthreads();
  if (threadIdx.x == 0) bsum[blockIdx.x] = s[0] + s[1] + s[2] + s[3];
}

// NB <= 512
__global__ __launch_bounds__(512) void scan_small_k(const int* __restrict__ bsum, int* __restrict__ boff, int NB){
  __shared__ int s[512];
  int t = threadIdx.x;
  int v = (t < NB) ? bsum[t] : 0;
  s[t] = v; __syncthreads();
  for (int off = 1; off < 512; off <<= 1){
    int x = (t >= off) ? s[t-off] : 0;
    __syncthreads();
    s[t] += x;
    __syncthreads();
  }
  if (t < NB) boff[t] = s[t] - v;  // exclusive
}

__global__ __launch_bounds__(256) void scan_final_k(const int* __restrict__ cnt, const int* __restrict__ boff,
                                                    int* __restrict__ rowptr, int* __restrict__ cursor,
                                                    float* __restrict__ dinv, int N){
  __shared__ int s[256];
  int t = threadIdx.x;
  int i = blockIdx.x*256 + t;
  int v = (i < N) ? cnt[i] : 0;
  s[t] = v; __syncthreads();
  for (int off = 1; off < 256; off <<= 1){
    int x = (t >= off) ? s[t-off] : 0;
    __syncthreads();
    s[t] += x;
    __syncthreads();
  }
  int excl = s[t] - v + boff[blockIdx.x];
  if (i < N){
    rowptr[i] = excl;
    cursor[i] = excl;
    dinv[i]   = rsqrtf((float)v + 1.0f);
    if (i == N-1) rowptr[N] = excl + v;
  }
}

__global__ __launch_bounds__(256) void fill_k(const int* __restrict__ src, const int* __restrict__ dst,
                                              int* __restrict__ cursor, int* __restrict__ col,
                                              float* __restrict__ wgt, const float* __restrict__ dinv, int E){
  int e = blockIdx.x*256 + threadIdx.x;
  if (e >= E) return;
  int s = src[e], d = dst[e];
  int pos = atomicAdd(&cursor[d], 1);
  col[pos] = s;
  wgt[pos] = dinv[s] * dinv[d];
}

// ---------------- GEMM: C[M,N] = act(A[M,K] @ B[K,N] + bias) ----------------
// Tile 64x64, 256 threads, 4x4 micro-tile per thread. K%16==0, N%64==0.

template<int ACT>
__global__ __launch_bounds__(256) void gemm_k(const float* __restrict__ A, const float* __restrict__ B,
                                              const float* __restrict__ bias, float* __restrict__ C,
                                              int M, int N, int K){
  __shared__ float As[16][68];   // [k][m]
  __shared__ float Bs[16][68];   // [k][n]
  int tid = threadIdx.x;
  int m0 = blockIdx.x * 64, n0 = blockIdx.y * 64;
  int ty = tid >> 4, tx = tid & 15;
  int lm = tid >> 2, lkq = tid & 3;   // A staging: row lm (0..63), k-quad lkq
  int lk = tid >> 4, ln4 = tid & 15;  // B staging: k-row lk (0..15), n-quad ln4
  int arow = m0 + lm; if (arow >= M) arow = M - 1;  // clamp; store is guarded

  float acc[4][4] = {{0.f}};

  for (int k0 = 0; k0 < K; k0 += 16){
    float4 av = *(const float4*)&A[(size_t)arow*K + k0 + lkq*4];
    float4 bv = *(const float4*)&B[(size_t)(k0+lk)*N + n0 + ln4*4];
    As[lkq*4+0][lm] = av.x; As[lkq*4+1][lm] = av.y; As[lkq*4+2][lm] = av.z; As[lkq*4+3][lm] = av.w;
    *(float4*)&Bs[lk][ln4*4] = bv;
    __syncthreads();
    #pragma unroll
    for (int kk = 0; kk < 16; ++kk){
      const float4 a = *(const float4*)&As[kk][ty*4];
      const float4 b = *(const float4*)&Bs[kk][tx*4];
      acc[0][0] += a.x*b.x; acc[0][1] += a.x*b.y; acc[0][2] += a.x*b.z; acc[0][3] += a.x*b.w;
      acc[1][0] += a.y*b.x; acc[1][1] += a.y*b.y; acc[1][2] += a.y*b.z; acc[1][3] += a.y*b.w;
      acc[2][0] += a.z*b.x; acc[2][1] += a.z*b.y; acc[2][2] += a.z*b.z; acc[2][3] += a.z*b.w;
      acc[3][0] += a.w*b.x; acc[3][1] += a.w*b.y; acc[3][2] += a.w*b.z; acc[3][3] += a.w*b.w;
    }
    __syncthreads();
  }

  float bv0 = 0.f, bv1 = 0.f, bv2 = 0.f, bv3 = 0.f;
  if (bias){
    const float4 b4 = *(const float4*)&bias[n0 + tx*4];
    bv0 = b4.x; bv1 = b4.y; bv2 = b4.z; bv3 = b4.w;
  }
  #pragma unroll
  for (int i = 0; i < 4; ++i){
    int r = m0 + ty*4 + i;
    if (r < M){
      float4 o;
      o.x = acc[i][0] + bv0; o.y = acc[i][1] + bv1; o.z = acc[i][2] + bv2; o.w = acc[i][3] + bv3;
      if (ACT == 1){ o.x = fmaxf(o.x,0.f); o.y = fmaxf(o.y,0.f); o.z = fmaxf(o.z,0.f); o.w = fmaxf(o.w,0.f); }
      *(float4*)&C[(size_t)r*N + n0 + tx*4] = o;
    }
  }
}

// ---------------- GCN aggregation + BN + ReLU (one wave per node) ----------------

__global__ __launch_bounds__(256) void agg_k(const float* __restrict__ hw, float* __restrict__ hout,
                                             const int* __restrict__ rowptr, const int* __restrict__ col,
                                             const float* __restrict__ wgt, const float* __restrict__ dinv,
                                             const float* __restrict__ bgnn, const float* __restrict__ gamma,
                                             const float* __restrict__ beta, const float* __restrict__ mean,
                                             const float* __restrict__ var, int N){
  int n = (blockIdx.x * blockDim.x + threadIdx.x) >> 6;
  int lane = threadIdx.x & 63;
  if (n >= N) return;
  int beg = rowptr[n], end = rowptr[n+1];
  int f = lane * 2;
  float ax = 0.f, ay = 0.f;
  for (int j = beg; j < end; ++j){
    int s = col[j];
    float w = wgt[j];
    const float2 v = *(const float2*)&hw[(size_t)s*128 + f];
    ax += w * v.x; ay += w * v.y;
  }
  float di = dinv[n], sw = di * di;
  const float2 hv = *(const float2*)&hw[(size_t)n*128 + f];
  ax += sw * hv.x + bgnn[f];
  ay += sw * hv.y + bgnn[f+1];
  float s0 = gamma[f]   * rsqrtf(var[f]   + 1e-5f);
  float s1 = gamma[f+1] * rsqrtf(var[f+1] + 1e-5f);
  float o0 = (ax - mean[f])   * s0 + beta[f];
  float o1 = (ay - mean[f+1]) * s1 + beta[f+1];
  o0 = fmaxf(o0, 0.f); o1 = fmaxf(o1, 0.f);
  *(float2*)&hout[(size_t)n*128 + f] = make_float2(o0, o1);
}

// ---------------- user gather, nlp-bias precompute, head ----------------

__global__ __launch_bounds__(256) void gather_k(const float* __restrict__ h, const int* __restrict__ uidx,
                                                float* __restrict__ uh, int B){
  int g = blockIdx.x*256 + threadIdx.x;
  if (g >= B*128) return;
  int i = g >> 7, f = g & 127;
  uh[g] = h[(size_t)uidx[i]*128 + f];
}

__global__ __launch_bounds__(256) void initc1_k(const float* __restrict__ b1, float* __restrict__ c1){
  c1[threadIdx.x] = b1[threadIdx.x];
}

// c1[c] += sum_d nlp[d] * W1[64+d][c]   (grid: 32 blocks = 4 col-groups x 8 d-groups)
__global__ __launch_bounds__(256) void c1acc_k(const float* __restrict__ nlp, const float* __restrict__ W1,
                                               float* __restrict__ c1, int NLP){
  int b = blockIdx.x;
  int c  = (b & 3) * 64 + (threadIdx.x & 63);
  int dq = threadIdx.x >> 6;
  int d0 = (b >> 2) * 99;
  float acc = 0.f;
  for (int d = d0 + dq; d < d0 + 99 && d < NLP; d += 4)
    acc += nlp[d] * W1[(size_t)(64 + d) * 256 + c];
  __shared__ float s[256];
  s[threadIdx.x] = acc; __syncthreads();
  if (dq == 0){
    float t = s[threadIdx.x] + s[threadIdx.x + 64] + s[threadIdx.x + 128] + s[threadIdx.x + 192];
    atomicAdd(&c1[c], t);
  }
}

// out[u] = sigmoid(z2[u,:] . W3 + b3); one wave per user
__global__ __launch_bounds__(256) void head_k(const float* __restrict__ z2, const float* __restrict__ W3,
                                              const float* __restrict__ b3, float* __restrict__ out, int B){
  int gid = blockIdx.x * blockDim.x + threadIdx.x;
  int u = gid >> 6, l = gid & 63;
  if (u >= B) return;
  float v = z2[(size_t)u*128 + l] * W3[l] + z2[(size_t)u*128 + 64 + l] * W3[64 + l];
  #pragma unroll
  for (int off = 32; off; off >>= 1) v += __shfl_down(v, off, 64);
  if (l == 0) out[u] = 1.f / (1.f + expf(-(v + b3[0])));
}

// ---------------- host ----------------

static void launch_gemm(int act, const float* A, const float* Bm, const float* bias, float* C,
                        int M, int N, int K, hipStream_t s){
  dim3 g((M + 63) / 64, N / 64);
  if (act) hipLaunchKernelGGL((gemm_k<1>), g, dim3(256), 0, s, A, Bm, bias, C, M, N, K);
  else     hipLaunchKernelGGL((gemm_k<0>), g, dim3(256), 0, s, A, Bm, bias, C, M, N, K);
}

extern "C" void kernel_launch(void* const* d_in, const int* in_sizes, int n_in,
                              void* d_out, int out_size, void* d_ws, size_t ws_size,
                              hipStream_t stream){
  const float* x     = (const float*)d_in[0];
  const float* nlp   = (const float*)d_in[1];
  const int*   eidx  = (const int*)  d_in[2];
  const int*   uidx  = (const int*)  d_in[3];
  const float* W_in  = (const float*)d_in[4];
  const float* b_in  = (const float*)d_in[5];
  const float* W_gnn = (const float*)d_in[6];
  const float* b_gnn = (const float*)d_in[7];
  const float* gam   = (const float*)d_in[8];
  const float* bet   = (const float*)d_in[9];
  const float* mean  = (const float*)d_in[10];
  const float* var   = (const float*)d_in[11];
  const float* Wproj = (const float*)d_in[12];
  const float* bproj = (const float*)d_in[13];
  const float* W1    = (const float*)d_in[14];
  const float* b1    = (const float*)d_in[15];
  const float* W2    = (const float*)d_in[16];
  const float* b2    = (const float*)d_in[17];
  const float* W3    = (const float*)d_in[18];
  const float* b3    = (const float*)d_in[19];
  float* out = (float*)d_out;

  const int N   = in_sizes[0] / 128;   // 100000
  const int E   = in_sizes[2] / 2;     // 1600000
  const int B   = in_sizes[3];         // 4096
  const int NLP = in_sizes[1];         // 786
  const int HID = 128;

  // workspace carve (256B aligned)
  char* p = (char*)d_ws;
  auto carve = [&](size_t bytes) -> void* {
    void* q = (void*)p;
    p += (bytes + 255) & ~(size_t)255;
    return q;
  };
  int*   cnt    = (int*)  carve((size_t)N * 4);
  int*   rowptr = (int*)  carve((size_t)(N + 1) * 4);
  int*   cursor = (int*)  carve((size_t)N * 4);
  int*   bsum   = (int*)  carve(512 * 4);
  int*   boff   = (int*)  carve(512 * 4);
  float* dinv   = (float*)carve((size_t)N * 4);
  int*   col    = (int*)  carve((size_t)E * 4);
  float* wgt    = (float*)carve((size_t)E * 4);
  float* h      = (float*)carve((size_t)N * HID * 4);
  float* hw     = (float*)carve((size_t)N * HID * 4);
  float* uh     = (float*)carve((size_t)B * HID * 4);
  float* embu   = (float*)carve((size_t)B * 64 * 4);
  float* z1     = (float*)carve((size_t)B * 256 * 4);
  float* z2     = (float*)carve((size_t)B * 128 * 4);
  float* c1     = (float*)carve(256 * 4);

  const int* src = eidx;
  const int* dst = eidx + E;

  const int NB = (N + 255) / 256;   // 391 (<512)

  // ---- CSR build ----
  hipMemsetAsync(cnt, 0, (size_t)N * 4, stream);
  hipLaunchKernelGGL(hist_k, dim3((E + 255) / 256), dim3(256), 0, stream, dst, cnt, E);
  hipLaunchKernelGGL(blocksum_k, dim3(NB), dim3(256), 0, stream, cnt, bsum, N);
  hipLaunchKernelGGL(scan_small_k, dim3(1), dim3(512), 0, stream, bsum, boff, NB);
  hipLaunchKernelGGL(scan_final_k, dim3(NB), dim3(256), 0, stream, cnt, boff, rowptr, cursor, dinv, N);
  hipLaunchKernelGGL(fill_k, dim3((E + 255) / 256), dim3(256), 0, stream, src, dst, cursor, col, wgt, dinv, E);

  // ---- input projection ----
  launch_gemm(1, x, W_in, b_in, h, N, HID, 128, stream);

  // ---- 3 GCN layers ----
  for (int i = 0; i < 3; ++i){
    launch_gemm(0, h, W_gnn + (size_t)i * 128 * 128, nullptr, hw, N, HID, 128, stream);
    hipLaunchKernelGGL(agg_k, dim3((N * 64 + 255) / 256), dim3(256), 0, stream,
                       hw, h, rowptr, col, wgt, dinv,
                       b_gnn + i * 128, gam + i * 128, bet + i * 128, mean + i * 128, var + i * 128, N);
  }

  // ---- user head ----
  hipLaunchKernelGGL(gather_k, dim3((B * 128 + 255) / 256), dim3(256), 0, stream, h, uidx, uh, B);
  hipLaunchKernelGGL(initc1_k, dim3(1), dim3(256), 0, stream, b1, c1);
  hipLaunchKernelGGL(c1acc_k, dim3(32), dim3(256), 0, stream, nlp, W1, c1, NLP);

  launch_gemm(0, uh, Wproj, bproj, embu, B, 64, 128, stream);   // emb_u = uh @ W_proj + b_proj
  launch_gemm(1, embu, W1, c1, z1, B, 256, 64, stream);         // z1 = relu(emb_u @ W1[:64] + c1)
  launch_gemm(1, z1, W2, b2, z2, B, 128, 256, stream);          // z2 = relu(z1 @ W2 + b2)
  hipLaunchKernelGGL(head_k, dim3((B * 64 + 255) / 256), dim3(256), 0, stream, z2, W3, b3, out, B);
}

// Round 2
// 902.865 us; speedup vs baseline: 1.2119x; 1.2119x over previous
//
#include <hip/hip_runtime.h>
#include <math.h>

// ---------------- CSR build ----------------

__global__ __launch_bounds__(256) void hist_k(const int* __restrict__ dst, int* __restrict__ cnt, int E){
  int e = blockIdx.x*256 + threadIdx.x;
  if (e < E) atomicAdd(&cnt[dst[e]], 1);
}

__global__ __launch_bounds__(256) void blocksum_k(const int* __restrict__ cnt, int* __restrict__ bsum, int N){
  int i = blockIdx.x*256 + threadIdx.x;
  int v = (i < N) ? cnt[i] : 0;
  #pragma unroll
  for (int off = 32; off; off >>= 1) v += __shfl_down(v, off, 64);
  __shared__ int s[4];
  if ((threadIdx.x & 63) == 0) s[threadIdx.x >> 6] = v;
  __syncthreads();
  if (threadIdx.x == 0) bsum[blockIdx.x] = s[0] + s[1] + s[2] + s[3];
}

// NB <= 512
__global__ __launch_bounds__(512) void scan_small_k(const int* __restrict__ bsum, int* __restrict__ boff, int NB){
  __shared__ int s[512];
  int t = threadIdx.x;
  int v = (t < NB) ? bsum[t] : 0;
  s[t] = v; __syncthreads();
  for (int off = 1; off < 512; off <<= 1){
    int x = (t >= off) ? s[t-off] : 0;
    __syncthreads();
    s[t] += x;
    __syncthreads();
  }
  if (t < NB) boff[t] = s[t] - v;  // exclusive
}

__global__ __launch_bounds__(256) void scan_final_k(const int* __restrict__ cnt, const int* __restrict__ boff,
                                                    int* __restrict__ rowptr, int* __restrict__ cursor,
                                                    float* __restrict__ dinv, int N){
  __shared__ int s[256];
  int t = threadIdx.x;
  int i = blockIdx.x*256 + t;
  int v = (i < N) ? cnt[i] : 0;
  s[t] = v; __syncthreads();
  for (int off = 1; off < 256; off <<= 1){
    int x = (t >= off) ? s[t-off] : 0;
    __syncthreads();
    s[t] += x;
    __syncthreads();
  }
  int excl = s[t] - v + boff[blockIdx.x];
  if (i < N){
    rowptr[i] = excl;
    cursor[i] = excl;
    dinv[i]   = rsqrtf((float)v + 1.0f);
    if (i == N-1) rowptr[N] = excl + v;
  }
}

__global__ __launch_bounds__(256) void fill_k(const int* __restrict__ src, const int* __restrict__ dst,
                                              int* __restrict__ cursor, int* __restrict__ col,
                                              float* __restrict__ wgt, const float* __restrict__ dinv, int E){
  int e = blockIdx.x*256 + threadIdx.x;
  if (e >= E) return;
  int s = src[e], d = dst[e];
  int pos = atomicAdd(&cursor[d], 1);
  col[pos] = s;
  wgt[pos] = dinv[s] * dinv[d];
}

// ---------------- GEMM 128x128 tile, 8x8 micro-tile (for big N=128 GEMMs) ----------------
// C[M,N] = act(A[M,K] @ B[K,N] + bias). Requires N%128==0, K%16==0.

template<int ACT>
__global__ __launch_bounds__(256) void gemm128_k(const float* __restrict__ A, const float* __restrict__ B,
                                                 const float* __restrict__ bias, float* __restrict__ C,
                                                 int M, int N, int K){
  __shared__ float As[16][132];
  __shared__ float Bs[16][132];
  const int tid = threadIdx.x;
  const int m0 = blockIdx.x * 128, n0 = blockIdx.y * 128;
  const int ty = tid >> 4, tx = tid & 15;          // compute coords
  const int sar = tid >> 1, sak = (tid & 1) * 8;   // A staging: row, k-offset
  const int sbk = tid >> 4, sbn = (tid & 15) * 8;  // B staging: k-row, col-offset
  int arow = m0 + sar; if (arow >= M) arow = M - 1;

  float acc[8][8];
  #pragma unroll
  for (int i = 0; i < 8; ++i)
    #pragma unroll
    for (int j = 0; j < 8; ++j) acc[i][j] = 0.f;

  for (int k0 = 0; k0 < K; k0 += 16){
    float4 a0 = *(const float4*)&A[(size_t)arow*K + k0 + sak];
    float4 a1 = *(const float4*)&A[(size_t)arow*K + k0 + sak + 4];
    float4 b0 = *(const float4*)&B[(size_t)(k0+sbk)*N + n0 + sbn];
    float4 b1 = *(const float4*)&B[(size_t)(k0+sbk)*N + n0 + sbn + 4];
    __syncthreads();  // previous iteration's reads complete before overwrite
    As[sak+0][sar]=a0.x; As[sak+1][sar]=a0.y; As[sak+2][sar]=a0.z; As[sak+3][sar]=a0.w;
    As[sak+4][sar]=a1.x; As[sak+5][sar]=a1.y; As[sak+6][sar]=a1.z; As[sak+7][sar]=a1.w;
    *(float4*)&Bs[sbk][sbn]   = b0;
    *(float4*)&Bs[sbk][sbn+4] = b1;
    __syncthreads();
    #pragma unroll
    for (int kk = 0; kk < 16; ++kk){
      const float4 av0 = *(const float4*)&As[kk][ty*4];
      const float4 av1 = *(const float4*)&As[kk][64 + ty*4];
      const float4 bv0 = *(const float4*)&Bs[kk][tx*4];
      const float4 bv1 = *(const float4*)&Bs[kk][64 + tx*4];
      const float a[8] = {av0.x,av0.y,av0.z,av0.w,av1.x,av1.y,av1.z,av1.w};
      const float b[8] = {bv0.x,bv0.y,bv0.z,bv0.w,bv1.x,bv1.y,bv1.z,bv1.w};
      #pragma unroll
      for (int i = 0; i < 8; ++i)
        #pragma unroll
        for (int j = 0; j < 8; ++j)
          acc[i][j] += a[i]*b[j];
    }
  }

  float bl[8] = {0,0,0,0,0,0,0,0};
  if (bias){
    const float4 x0 = *(const float4*)&bias[n0 + tx*4];
    const float4 x1 = *(const float4*)&bias[n0 + 64 + tx*4];
    bl[0]=x0.x; bl[1]=x0.y; bl[2]=x0.z; bl[3]=x0.w;
    bl[4]=x1.x; bl[5]=x1.y; bl[6]=x1.z; bl[7]=x1.w;
  }
  #pragma unroll
  for (int i = 0; i < 8; ++i){
    int r = m0 + (i>>2)*64 + ty*4 + (i&3);
    if (r < M){
      float4 o0, o1;
      o0.x = acc[i][0]+bl[0]; o0.y = acc[i][1]+bl[1]; o0.z = acc[i][2]+bl[2]; o0.w = acc[i][3]+bl[3];
      o1.x = acc[i][4]+bl[4]; o1.y = acc[i][5]+bl[5]; o1.z = acc[i][6]+bl[6]; o1.w = acc[i][7]+bl[7];
      if (ACT == 1){
        o0.x=fmaxf(o0.x,0.f); o0.y=fmaxf(o0.y,0.f); o0.z=fmaxf(o0.z,0.f); o0.w=fmaxf(o0.w,0.f);
        o1.x=fmaxf(o1.x,0.f); o1.y=fmaxf(o1.y,0.f); o1.z=fmaxf(o1.z,0.f); o1.w=fmaxf(o1.w,0.f);
      }
      *(float4*)&C[(size_t)r*N + n0 + tx*4]      = o0;
      *(float4*)&C[(size_t)r*N + n0 + 64 + tx*4] = o1;
    }
  }
}

// ---------------- GEMM 64x64 (small head GEMMs) ----------------

template<int ACT>
__global__ __launch_bounds__(256) void gemm_k(const float* __restrict__ A, const float* __restrict__ B,
                                              const float* __restrict__ bias, float* __restrict__ C,
                                              int M, int N, int K){
  __shared__ float As[16][68];
  __shared__ float Bs[16][68];
  int tid = threadIdx.x;
  int m0 = blockIdx.x * 64, n0 = blockIdx.y * 64;
  int ty = tid >> 4, tx = tid & 15;
  int lm = tid >> 2, lkq = tid & 3;
  int lk = tid >> 4, ln4 = tid & 15;
  int arow = m0 + lm; if (arow >= M) arow = M - 1;

  float acc[4][4] = {{0.f}};

  for (int k0 = 0; k0 < K; k0 += 16){
    float4 av = *(const float4*)&A[(size_t)arow*K + k0 + lkq*4];
    float4 bv = *(const float4*)&B[(size_t)(k0+lk)*N + n0 + ln4*4];
    As[lkq*4+0][lm] = av.x; As[lkq*4+1][lm] = av.y; As[lkq*4+2][lm] = av.z; As[lkq*4+3][lm] = av.w;
    *(float4*)&Bs[lk][ln4*4] = bv;
    __syncthreads();
    #pragma unroll
    for (int kk = 0; kk < 16; ++kk){
      const float4 a = *(const float4*)&As[kk][ty*4];
      const float4 b = *(const float4*)&Bs[kk][tx*4];
      acc[0][0] += a.x*b.x; acc[0][1] += a.x*b.y; acc[0][2] += a.x*b.z; acc[0][3] += a.x*b.w;
      acc[1][0] += a.y*b.x; acc[1][1] += a.y*b.y; acc[1][2] += a.y*b.z; acc[1][3] += a.y*b.w;
      acc[2][0] += a.z*b.x; acc[2][1] += a.z*b.y; acc[2][2] += a.z*b.z; acc[2][3] += a.z*b.w;
      acc[3][0] += a.w*b.x; acc[3][1] += a.w*b.y; acc[3][2] += a.w*b.z; acc[3][3] += a.w*b.w;
    }
    __syncthreads();
  }

  float bv0 = 0.f, bv1 = 0.f, bv2 = 0.f, bv3 = 0.f;
  if (bias){
    const float4 b4 = *(const float4*)&bias[n0 + tx*4];
    bv0 = b4.x; bv1 = b4.y; bv2 = b4.z; bv3 = b4.w;
  }
  #pragma unroll
  for (int i = 0; i < 4; ++i){
    int r = m0 + ty*4 + i;
    if (r < M){
      float4 o;
      o.x = acc[i][0] + bv0; o.y = acc[i][1] + bv1; o.z = acc[i][2] + bv2; o.w = acc[i][3] + bv3;
      if (ACT == 1){ o.x = fmaxf(o.x,0.f); o.y = fmaxf(o.y,0.f); o.z = fmaxf(o.z,0.f); o.w = fmaxf(o.w,0.f); }
      *(float4*)&C[(size_t)r*N + n0 + tx*4] = o;
    }
  }
}

// ---------------- GCN aggregation + BN + ReLU ----------------
// One wave per node; two 32-lane halves own alternate edges (float4/lane),
// edge loop unrolled 2x per half -> 4 row-loads in flight per wave.

__global__ __launch_bounds__(256) void agg_k(const float* __restrict__ hw, float* __restrict__ hout,
                                             const int* __restrict__ rowptr, const int* __restrict__ col,
                                             const float* __restrict__ wgt, const float* __restrict__ dinv,
                                             const float* __restrict__ bgnn, const float* __restrict__ gamma,
                                             const float* __restrict__ beta, const float* __restrict__ mean,
                                             const float* __restrict__ var, int N){
  int n = (blockIdx.x * blockDim.x + threadIdx.x) >> 6;
  if (n >= N) return;
  int lane = threadIdx.x & 63;
  int half = lane >> 5;
  int sl   = lane & 31;
  int f    = sl * 4;
  int beg = rowptr[n], end = rowptr[n+1];

  float4 a0 = make_float4(0.f,0.f,0.f,0.f);
  float4 a1 = make_float4(0.f,0.f,0.f,0.f);

  int j = beg + half;
  for (; j + 2 < end; j += 4){
    int   s0 = col[j],  s1 = col[j+2];
    float w0 = wgt[j],  w1 = wgt[j+2];
    const float4 v0 = *(const float4*)&hw[(size_t)s0*128 + f];
    const float4 v1 = *(const float4*)&hw[(size_t)s1*128 + f];
    a0.x += w0*v0.x; a0.y += w0*v0.y; a0.z += w0*v0.z; a0.w += w0*v0.w;
    a1.x += w1*v1.x; a1.y += w1*v1.y; a1.z += w1*v1.z; a1.w += w1*v1.w;
  }
  if (j < end){
    int s0 = col[j]; float w0 = wgt[j];
    const float4 v0 = *(const float4*)&hw[(size_t)s0*128 + f];
    a0.x += w0*v0.x; a0.y += w0*v0.y; a0.z += w0*v0.z; a0.w += w0*v0.w;
  }
  a0.x += a1.x; a0.y += a1.y; a0.z += a1.z; a0.w += a1.w;

  // combine the two halves (lane ^ 32)
  a0.x += __shfl_xor(a0.x, 32, 64);
  a0.y += __shfl_xor(a0.y, 32, 64);
  a0.z += __shfl_xor(a0.z, 32, 64);
  a0.w += __shfl_xor(a0.w, 32, 64);

  if (half == 0){
    float di = dinv[n], sw = di * di;
    const float4 hv = *(const float4*)&hw[(size_t)n*128 + f];
    const float4 bg = *(const float4*)&bgnn[f];
    const float4 gm = *(const float4*)&gamma[f];
    const float4 bt = *(const float4*)&beta[f];
    const float4 mn = *(const float4*)&mean[f];
    const float4 vr = *(const float4*)&var[f];
    float4 o;
    o.x = (a0.x + sw*hv.x + bg.x - mn.x) * (gm.x * rsqrtf(vr.x + 1e-5f)) + bt.x;
    o.y = (a0.y + sw*hv.y + bg.y - mn.y) * (gm.y * rsqrtf(vr.y + 1e-5f)) + bt.y;
    o.z = (a0.z + sw*hv.z + bg.z - mn.z) * (gm.z * rsqrtf(vr.z + 1e-5f)) + bt.z;
    o.w = (a0.w + sw*hv.w + bg.w - mn.w) * (gm.w * rsqrtf(vr.w + 1e-5f)) + bt.w;
    o.x = fmaxf(o.x, 0.f); o.y = fmaxf(o.y, 0.f); o.z = fmaxf(o.z, 0.f); o.w = fmaxf(o.w, 0.f);
    *(float4*)&hout[(size_t)n*128 + f] = o;
  }
}

// ---------------- user gather, nlp-bias precompute, head ----------------

__global__ __launch_bounds__(256) void gather_k(const float* __restrict__ h, const int* __restrict__ uidx,
                                                float* __restrict__ uh, int B){
  int g = blockIdx.x*256 + threadIdx.x;
  if (g >= B*128) return;
  int i = g >> 7, f = g & 127;
  uh[g] = h[(size_t)uidx[i]*128 + f];
}

__global__ __launch_bounds__(256) void initc1_k(const float* __restrict__ b1, float* __restrict__ c1){
  c1[threadIdx.x] = b1[threadIdx.x];
}

__global__ __launch_bounds__(256) void c1acc_k(const float* __restrict__ nlp, const float* __restrict__ W1,
                                               float* __restrict__ c1, int NLP){
  int b = blockIdx.x;
  int c  = (b & 3) * 64 + (threadIdx.x & 63);
  int dq = threadIdx.x >> 6;
  int d0 = (b >> 2) * 99;
  float acc = 0.f;
  for (int d = d0 + dq; d < d0 + 99 && d < NLP; d += 4)
    acc += nlp[d] * W1[(size_t)(64 + d) * 256 + c];
  __shared__ float s[256];
  s[threadIdx.x] = acc; __syncthreads();
  if (dq == 0){
    float t = s[threadIdx.x] + s[threadIdx.x + 64] + s[threadIdx.x + 128] + s[threadIdx.x + 192];
    atomicAdd(&c1[c], t);
  }
}

__global__ __launch_bounds__(256) void head_k(const float* __restrict__ z2, const float* __restrict__ W3,
                                              const float* __restrict__ b3, float* __restrict__ out, int B){
  int gid = blockIdx.x * blockDim.x + threadIdx.x;
  int u = gid >> 6, l = gid & 63;
  if (u >= B) return;
  float v = z2[(size_t)u*128 + l] * W3[l] + z2[(size_t)u*128 + 64 + l] * W3[64 + l];
  #pragma unroll
  for (int off = 32; off; off >>= 1) v += __shfl_down(v, off, 64);
  if (l == 0) out[u] = 1.f / (1.f + expf(-(v + b3[0])));
}

// ---------------- host ----------------

static void launch_gemm128(int act, const float* A, const float* Bm, const float* bias, float* C,
                           int M, int N, int K, hipStream_t s){
  dim3 g((M + 127) / 128, N / 128);
  if (act) hipLaunchKernelGGL((gemm128_k<1>), g, dim3(256), 0, s, A, Bm, bias, C, M, N, K);
  else     hipLaunchKernelGGL((gemm128_k<0>), g, dim3(256), 0, s, A, Bm, bias, C, M, N, K);
}

static void launch_gemm(int act, const float* A, const float* Bm, const float* bias, float* C,
                        int M, int N, int K, hipStream_t s){
  dim3 g((M + 63) / 64, N / 64);
  if (act) hipLaunchKernelGGL((gemm_k<1>), g, dim3(256), 0, s, A, Bm, bias, C, M, N, K);
  else     hipLaunchKernelGGL((gemm_k<0>), g, dim3(256), 0, s, A, Bm, bias, C, M, N, K);
}

extern "C" void kernel_launch(void* const* d_in, const int* in_sizes, int n_in,
                              void* d_out, int out_size, void* d_ws, size_t ws_size,
                              hipStream_t stream){
  const float* x     = (const float*)d_in[0];
  const float* nlp   = (const float*)d_in[1];
  const int*   eidx  = (const int*)  d_in[2];
  const int*   uidx  = (const int*)  d_in[3];
  const float* W_in  = (const float*)d_in[4];
  const float* b_in  = (const float*)d_in[5];
  const float* W_gnn = (const float*)d_in[6];
  const float* b_gnn = (const float*)d_in[7];
  const float* gam   = (const float*)d_in[8];
  const float* bet   = (const float*)d_in[9];
  const float* mean  = (const float*)d_in[10];
  const float* var   = (const float*)d_in[11];
  const float* Wproj = (const float*)d_in[12];
  const float* bproj = (const float*)d_in[13];
  const float* W1    = (const float*)d_in[14];
  const float* b1    = (const float*)d_in[15];
  const float* W2    = (const float*)d_in[16];
  const float* b2    = (const float*)d_in[17];
  const float* W3    = (const float*)d_in[18];
  const float* b3    = (const float*)d_in[19];
  float* out = (float*)d_out;

  const int N   = in_sizes[0] / 128;   // 100000
  const int E   = in_sizes[2] / 2;     // 1600000
  const int B   = in_sizes[3];         // 4096
  const int NLP = in_sizes[1];         // 786
  const int HID = 128;

  char* p = (char*)d_ws;
  auto carve = [&](size_t bytes) -> void* {
    void* q = (void*)p;
    p += (bytes + 255) & ~(size_t)255;
    return q;
  };
  int*   cnt    = (int*)  carve((size_t)N * 4);
  int*   rowptr = (int*)  carve((size_t)(N + 1) * 4);
  int*   cursor = (int*)  carve((size_t)N * 4);
  int*   bsum   = (int*)  carve(512 * 4);
  int*   boff   = (int*)  carve(512 * 4);
  float* dinv   = (float*)carve((size_t)N * 4);
  int*   col    = (int*)  carve((size_t)E * 4);
  float* wgt    = (float*)carve((size_t)E * 4);
  float* h      = (float*)carve((size_t)N * HID * 4);
  float* hw     = (float*)carve((size_t)N * HID * 4);
  float* uh     = (float*)carve((size_t)B * HID * 4);
  float* embu   = (float*)carve((size_t)B * 64 * 4);
  float* z1     = (float*)carve((size_t)B * 256 * 4);
  float* z2     = (float*)carve((size_t)B * 128 * 4);
  float* c1     = (float*)carve(256 * 4);

  const int* src = eidx;
  const int* dst = eidx + E;

  const int NB = (N + 255) / 256;   // 391 (<512)

  // ---- CSR build ----
  hipMemsetAsync(cnt, 0, (size_t)N * 4, stream);
  hipLaunchKernelGGL(hist_k, dim3((E + 255) / 256), dim3(256), 0, stream, dst, cnt, E);
  hipLaunchKernelGGL(blocksum_k, dim3(NB), dim3(256), 0, stream, cnt, bsum, N);
  hipLaunchKernelGGL(scan_small_k, dim3(1), dim3(512), 0, stream, bsum, boff, NB);
  hipLaunchKernelGGL(scan_final_k, dim3(NB), dim3(256), 0, stream, cnt, boff, rowptr, cursor, dinv, N);
  hipLaunchKernelGGL(fill_k, dim3((E + 255) / 256), dim3(256), 0, stream, src, dst, cursor, col, wgt, dinv, E);

  // ---- input projection ----
  launch_gemm128(1, x, W_in, b_in, h, N, HID, 128, stream);

  // ---- 3 GCN layers ----
  for (int i = 0; i < 3; ++i){
    launch_gemm128(0, h, W_gnn + (size_t)i * 128 * 128, nullptr, hw, N, HID, 128, stream);
    hipLaunchKernelGGL(agg_k, dim3((N * 64 + 255) / 256), dim3(256), 0, stream,
                       hw, h, rowptr, col, wgt, dinv,
                       b_gnn + i * 128, gam + i * 128, bet + i * 128, mean + i * 128, var + i * 128, N);
  }

  // ---- user head ----
  hipLaunchKernelGGL(gather_k, dim3((B * 128 + 255) / 256), dim3(256), 0, stream, h, uidx, uh, B);
  hipLaunchKernelGGL(initc1_k, dim3(1), dim3(256), 0, stream, b1, c1);
  hipLaunchKernelGGL(c1acc_k, dim3(32), dim3(256), 0, stream, nlp, W1, c1, NLP);

  launch_gemm(0, uh, Wproj, bproj, embu, B, 64, 128, stream);
  launch_gemm(1, embu, W1, c1, z1, B, 256, 64, stream);
  launch_gemm(1, z1, W2, b2, z2, B, 128, 256, stream);
  hipLaunchKernelGGL(head_k, dim3((B * 64 + 255) / 256), dim3(256), 0, stream, z2, W3, b3, out, B);
}